// Round 10
// baseline (418.911 us; speedup 1.0000x reference)
//
#include <hip/hip_runtime.h>
#include <math.h>

#define H 1024
#define N 512
#define M 128
#define NM 65536
#define EPSV 1e-8f
#define DOT_BLOCKS 4096   // 1024 thr = 16 waves = 16 We-rows per block

typedef float f32x4 __attribute__((ext_vector_type(4)));

__device__ __forceinline__ float wave_reduce_sum(float v) {
#pragma unroll
    for (int off = 32; off > 0; off >>= 1)
        v += __shfl_xor(v, off, 64);
    return v;
}

// ws layout (floats): [0..127]=k (unused by epilogue)  [128..255]=a
//                     [512..512+NM)=raw We dots
// out layout (floats): [0..127]=read  [128..639]=state  [640..)=new_memory
//
// Kernel 1: blocks 0..4095 stream We (NT) and store raw dots; block 4096
// concurrently does proj (k,a,beta,g) + addressing (cos/softmax/state/read).
// No inter-block dependency; writes disjoint.
__global__ void __launch_bounds__(1024)
fused1_kernel(const float* __restrict__ x, const float* __restrict__ We,
              const float* __restrict__ Wk, const float* __restrict__ bk,
              const float* __restrict__ Wa, const float* __restrict__ ba,
              const float* __restrict__ Wbeta, const float* __restrict__ bbeta,
              const float* __restrict__ Wg, const float* __restrict__ bg,
              const float* __restrict__ mem, const float* __restrict__ prev,
              float* __restrict__ ws, float* __restrict__ out) {
    __shared__ float xs[H];
    __shared__ float sk[M];
    __shared__ float swc[N];
    __shared__ float sst[N];
    __shared__ float spart[8][M];
    __shared__ float sred[16];
    __shared__ float s_kn, s_mx, s_sum, s_beta, s_g;

    const int tid  = threadIdx.x;
    const int lane = tid & 63;
    const int wid  = tid >> 6;

    // stage x (4 KB) in LDS
    if (tid < 256)
        reinterpret_cast<f32x4*>(xs)[tid] = reinterpret_cast<const f32x4*>(x)[tid];
    __syncthreads();
    const f32x4* xls = reinterpret_cast<const f32x4*>(xs);

    if (blockIdx.x < DOT_BLOCKS) {
        // ---- We dots: one wave per row, NT stream ----
        const int r = blockIdx.x * 16 + wid;
        const f32x4* wrow = reinterpret_cast<const f32x4*>(We + (size_t)r * H);
        float acc = 0.f;
#pragma unroll
        for (int it = 0; it < 4; ++it) {
            const int idx = it * 64 + lane;
            const f32x4 wv = __builtin_nontemporal_load(wrow + idx);
            const f32x4 xv = xls[idx];
            acc = fmaf(wv.x, xv.x, acc);
            acc = fmaf(wv.y, xv.y, acc);
            acc = fmaf(wv.z, xv.z, acc);
            acc = fmaf(wv.w, xv.w, acc);
        }
        acc = wave_reduce_sum(acc);
        if (lane == 0) ws[512 + r] = acc;          // raw dot; be added in epilogue
        return;
    }

    // ================= block DOT_BLOCKS: proj + addressing =================
    // ---- proj: 258 wave-tasks over 16 waves ----
    for (int task = wid; task < 258; task += 16) {
        const float* wrow;
        float bias;
        if (task < 128)      { wrow = Wk + task * H;         bias = bk[task]; }
        else if (task < 256) { wrow = Wa + (task - 128) * H; bias = ba[task - 128]; }
        else if (task == 256){ wrow = Wbeta;                 bias = bbeta[0]; }
        else                 { wrow = Wg;                    bias = bg[0]; }

        const f32x4* wv4 = reinterpret_cast<const f32x4*>(wrow);
        float acc = 0.f;
#pragma unroll
        for (int it = 0; it < 4; ++it) {
            const int idx = it * 64 + lane;
            const f32x4 wv = wv4[idx];
            const f32x4 xv = xls[idx];
            acc = fmaf(wv.x, xv.x, acc);
            acc = fmaf(wv.y, xv.y, acc);
            acc = fmaf(wv.z, xv.z, acc);
            acc = fmaf(wv.w, xv.w, acc);
        }
        acc = wave_reduce_sum(acc);
        if (lane == 0) {
            const float z = acc + bias;
            if (task < 128)       sk[task] = z;                     // k -> shared
            else if (task < 256)  ws[task] = z;                     // a -> ws (epilogue)
            else if (task == 256) s_beta = fmaxf(z, 0.f) + log1pf(expf(-fabsf(z)));
            else                  s_g    = 1.f / (1.f + expf(-z));
        }
    }
    __syncthreads();

    // ---- kn = max(||k||, eps) ----
    float pk = 0.f;
    if (tid < M) { const float kv = sk[tid]; pk = kv * kv; }
    float rsum = wave_reduce_sum(pk);
    if (lane == 0) sred[wid] = rsum;
    __syncthreads();
    if (tid == 0) {
        float s = 0.f;
        for (int i = 0; i < 16; ++i) s += sred[i];
        s_kn = fmaxf(sqrtf(s), EPSV);
    }
    __syncthreads();
    const float beta = s_beta;
    const float g    = s_g;
    const float kn   = s_kn;

    // ---- beta * cos[n], one wave per mem row ----
    for (int n = wid; n < N; n += 16) {
        const float* row = mem + n * M;
        const float a0 = row[lane], a1 = row[lane + 64];
        float d = fmaf(a0, sk[lane], a1 * sk[lane + 64]);
        float q = fmaf(a0, a0, a1 * a1);
#pragma unroll
        for (int off = 32; off > 0; off >>= 1) {
            d += __shfl_xor(d, off, 64);
            q += __shfl_xor(q, off, 64);
        }
        if (lane == 0) {
            const float mn = fmaxf(sqrtf(q), EPSV);
            swc[n] = beta * (d / (mn * kn));
        }
    }
    __syncthreads();

    // ---- softmax over N=512 + gated interpolation ----
    const float v = (tid < N) ? swc[tid] : -INFINITY;
    float mx = v;
#pragma unroll
    for (int off = 32; off > 0; off >>= 1) mx = fmaxf(mx, __shfl_xor(mx, off, 64));
    if (lane == 0) sred[wid] = mx;
    __syncthreads();
    if (tid == 0) {
        float m2 = -INFINITY;
        for (int i = 0; i < 16; ++i) m2 = fmaxf(m2, sred[i]);
        s_mx = m2;
    }
    __syncthreads();
    const float ex = (tid < N) ? expf(v - s_mx) : 0.f;
    float se = wave_reduce_sum(ex);
    if (lane == 0) sred[wid] = se;
    __syncthreads();
    if (tid == 0) {
        float s = 0.f;
        for (int i = 0; i < 16; ++i) s += sred[i];
        s_sum = s;
    }
    __syncthreads();
    if (tid < N) {
        const float st = g * (ex / s_sum) + (1.f - g) * prev[tid];
        sst[tid] = st;
        out[M + tid] = st;          // state output (read by epilogue)
    }
    __syncthreads();

    // ---- read = state @ mem ----
    const int t = tid & 127, j = tid >> 7;
    float p = 0.f;
    const int n0 = j * 64;
    for (int n = n0; n < n0 + 64; ++n)
        p = fmaf(sst[n], mem[n * M + t], p);
    spart[j][t] = p;
    __syncthreads();
    if (tid < M) {
        float s = 0.f;
#pragma unroll
        for (int jj = 0; jj < 8; ++jj) s += spart[jj][tid];
        out[tid] = s;               // read output
    }
}

// Kernel 2: epilogue — E = sigmoid(dot+be); nm = mem*(1-st*E) + st*a.
// 64 blocks x 256 thr x f32x4. ~1 MB traffic, ~3 us.
__global__ void __launch_bounds__(256)
epilogue_kernel(const float* __restrict__ ws, const float* __restrict__ be,
                const float* __restrict__ mem, const float* __restrict__ state,
                float* __restrict__ nm) {
    const int i = blockIdx.x * 256 + threadIdx.x;    // f32x4 index, 0..16383
    const int r = i * 4;
    const f32x4 d  = reinterpret_cast<const f32x4*>(ws + 512)[i];
    const f32x4 bv = reinterpret_cast<const f32x4*>(be)[i];
    const f32x4 mv = reinterpret_cast<const f32x4*>(mem)[i];
    const float st = state[r >> 7];
    const f32x4 av = *reinterpret_cast<const f32x4*>(ws + 128 + (r & 127));
    f32x4 o;
    o.x = mv.x * (1.f - st * (1.f / (1.f + expf(-(d.x + bv.x))))) + st * av.x;
    o.y = mv.y * (1.f - st * (1.f / (1.f + expf(-(d.y + bv.y))))) + st * av.y;
    o.z = mv.z * (1.f - st * (1.f / (1.f + expf(-(d.z + bv.z))))) + st * av.z;
    o.w = mv.w * (1.f - st * (1.f / (1.f + expf(-(d.w + bv.w))))) + st * av.w;
    __builtin_nontemporal_store(o, reinterpret_cast<f32x4*>(nm) + i);
}

// ---------------------------------------------------------------------------
extern "C" void kernel_launch(void* const* d_in, const int* in_sizes, int n_in,
                              void* d_out, int out_size, void* d_ws, size_t ws_size,
                              hipStream_t stream) {
    const float* x     = (const float*)d_in[0];
    const float* prev  = (const float*)d_in[1];
    const float* mem   = (const float*)d_in[2];
    const float* Wk    = (const float*)d_in[3];
    const float* bk    = (const float*)d_in[4];
    const float* Wbeta = (const float*)d_in[5];
    const float* bbeta = (const float*)d_in[6];
    const float* Wg    = (const float*)d_in[7];
    const float* bg    = (const float*)d_in[8];
    // d_in[9]=Ws, d_in[10]=bs, d_in[11]=Wgamma, d_in[12]=bgamma : dead outputs, skipped
    const float* We    = (const float*)d_in[13];
    const float* be    = (const float*)d_in[14];
    const float* Wa    = (const float*)d_in[15];
    const float* ba    = (const float*)d_in[16];

    float* out = (float*)d_out;   // [0..127]=read [128..639]=state [640..)=new_memory
    float* ws  = (float*)d_ws;    // [0..255]=k,a  [512..)=dots

    fused1_kernel<<<DOT_BLOCKS + 1, 1024, 0, stream>>>(
        x, We, Wk, bk, Wa, ba, Wbeta, bbeta, Wg, bg, mem, prev, ws, out);
    epilogue_kernel<<<NM / (256 * 4), 256, 0, stream>>>(
        ws, be, mem, out + M, out + M + N);
}

// Round 12
// 389.525 us; speedup vs baseline: 1.0754x; 1.0754x over previous
//
#include <hip/hip_runtime.h>
#include <math.h>

#define H 1024
#define N 512
#define M 128
#define NM 65536
#define EPSV 1e-8f
#define DOT_BLOCKS 4096   // 1024 thr = 16 waves = 16 We-rows per block

typedef float f32x4 __attribute__((ext_vector_type(4)));

__device__ __forceinline__ float wave_reduce_sum(float v) {
#pragma unroll
    for (int off = 32; off > 0; off >>= 1)
        v += __shfl_xor(v, off, 64);
    return v;
}

// ws layout (floats): [0..127]=k (unused by epilogue)  [128..255]=a
//                     [512..512+NM)=raw We dots
// out layout (floats): [0..127]=read  [128..639]=state  [640..)=new_memory
//
// Kernel 1: block 0 does proj (k,a,beta,g) + addressing (cos/softmax/state/
// read) — dispatched FIRST so it overlaps under the We stream. Blocks
// 1..4096 stream We (NT) and store raw dots. Disjoint writes, no
// inter-block dependency.
__global__ void __launch_bounds__(1024)
fused1_kernel(const float* __restrict__ x, const float* __restrict__ We,
              const float* __restrict__ Wk, const float* __restrict__ bk,
              const float* __restrict__ Wa, const float* __restrict__ ba,
              const float* __restrict__ Wbeta, const float* __restrict__ bbeta,
              const float* __restrict__ Wg, const float* __restrict__ bg,
              const float* __restrict__ mem, const float* __restrict__ prev,
              float* __restrict__ ws, float* __restrict__ out) {
    __shared__ float xs[H];
    __shared__ float sk[M];
    __shared__ float swc[N];
    __shared__ float sst[N];
    __shared__ float spart[8][M];
    __shared__ float sred[16];
    __shared__ float s_kn, s_mx, s_sum, s_beta, s_g;

    const int tid  = threadIdx.x;
    const int lane = tid & 63;
    const int wid  = tid >> 6;

    // stage x (4 KB) in LDS
    if (tid < 256)
        reinterpret_cast<f32x4*>(xs)[tid] = reinterpret_cast<const f32x4*>(x)[tid];
    __syncthreads();
    const f32x4* xls = reinterpret_cast<const f32x4*>(xs);

    if (blockIdx.x != 0) {
        // ---- We dots: one wave per row, NT stream ----
        const int r = (blockIdx.x - 1) * 16 + wid;
        const f32x4* wrow = reinterpret_cast<const f32x4*>(We + (size_t)r * H);
        float acc = 0.f;
#pragma unroll
        for (int it = 0; it < 4; ++it) {
            const int idx = it * 64 + lane;
            const f32x4 wv = __builtin_nontemporal_load(wrow + idx);
            const f32x4 xv = xls[idx];
            acc = fmaf(wv.x, xv.x, acc);
            acc = fmaf(wv.y, xv.y, acc);
            acc = fmaf(wv.z, xv.z, acc);
            acc = fmaf(wv.w, xv.w, acc);
        }
        acc = wave_reduce_sum(acc);
        if (lane == 0) ws[512 + r] = acc;          // raw dot; be added in epilogue
        return;
    }

    // ================= block 0: proj + addressing (overlapped) =============
    // ---- proj: 258 wave-tasks over 16 waves ----
    for (int task = wid; task < 258; task += 16) {
        const float* wrow;
        float bias;
        if (task < 128)      { wrow = Wk + task * H;         bias = bk[task]; }
        else if (task < 256) { wrow = Wa + (task - 128) * H; bias = ba[task - 128]; }
        else if (task == 256){ wrow = Wbeta;                 bias = bbeta[0]; }
        else                 { wrow = Wg;                    bias = bg[0]; }

        const f32x4* wv4 = reinterpret_cast<const f32x4*>(wrow);
        float acc = 0.f;
#pragma unroll
        for (int it = 0; it < 4; ++it) {
            const int idx = it * 64 + lane;
            const f32x4 wv = wv4[idx];
            const f32x4 xv = xls[idx];
            acc = fmaf(wv.x, xv.x, acc);
            acc = fmaf(wv.y, xv.y, acc);
            acc = fmaf(wv.z, xv.z, acc);
            acc = fmaf(wv.w, xv.w, acc);
        }
        acc = wave_reduce_sum(acc);
        if (lane == 0) {
            const float z = acc + bias;
            if (task < 128)       sk[task] = z;                     // k -> shared
            else if (task < 256)  ws[task] = z;                     // a -> ws (epilogue)
            else if (task == 256) s_beta = fmaxf(z, 0.f) + log1pf(expf(-fabsf(z)));
            else                  s_g    = 1.f / (1.f + expf(-z));
        }
    }
    __syncthreads();

    // ---- kn = max(||k||, eps) ----
    float pk = 0.f;
    if (tid < M) { const float kv = sk[tid]; pk = kv * kv; }
    float rsum = wave_reduce_sum(pk);
    if (lane == 0) sred[wid] = rsum;
    __syncthreads();
    if (tid == 0) {
        float s = 0.f;
        for (int i = 0; i < 16; ++i) s += sred[i];
        s_kn = fmaxf(sqrtf(s), EPSV);
    }
    __syncthreads();
    const float beta = s_beta;
    const float g    = s_g;
    const float kn   = s_kn;

    // ---- beta * cos[n], one wave per mem row ----
    for (int n = wid; n < N; n += 16) {
        const float* row = mem + n * M;
        const float a0 = row[lane], a1 = row[lane + 64];
        float d = fmaf(a0, sk[lane], a1 * sk[lane + 64]);
        float q = fmaf(a0, a0, a1 * a1);
#pragma unroll
        for (int off = 32; off > 0; off >>= 1) {
            d += __shfl_xor(d, off, 64);
            q += __shfl_xor(q, off, 64);
        }
        if (lane == 0) {
            const float mn = fmaxf(sqrtf(q), EPSV);
            swc[n] = beta * (d / (mn * kn));
        }
    }
    __syncthreads();

    // ---- softmax over N=512 + gated interpolation ----
    const float v = (tid < N) ? swc[tid] : -INFINITY;
    float mx = v;
#pragma unroll
    for (int off = 32; off > 0; off >>= 1) mx = fmaxf(mx, __shfl_xor(mx, off, 64));
    if (lane == 0) sred[wid] = mx;
    __syncthreads();
    if (tid == 0) {
        float m2 = -INFINITY;
        for (int i = 0; i < 16; ++i) m2 = fmaxf(m2, sred[i]);
        s_mx = m2;
    }
    __syncthreads();
    const float ex = (tid < N) ? expf(v - s_mx) : 0.f;
    float se = wave_reduce_sum(ex);
    if (lane == 0) sred[wid] = se;
    __syncthreads();
    if (tid == 0) {
        float s = 0.f;
        for (int i = 0; i < 16; ++i) s += sred[i];
        s_sum = s;
    }
    __syncthreads();
    if (tid < N) {
        const float st = g * (ex / s_sum) + (1.f - g) * prev[tid];
        sst[tid] = st;
        out[M + tid] = st;          // state output (read by epilogue)
    }
    __syncthreads();

    // ---- read = state @ mem ----
    const int t = tid & 127, j = tid >> 7;
    float p = 0.f;
    const int n0 = j * 64;
    for (int n = n0; n < n0 + 64; ++n)
        p = fmaf(sst[n], mem[n * M + t], p);
    spart[j][t] = p;
    __syncthreads();
    if (tid < M) {
        float s = 0.f;
#pragma unroll
        for (int jj = 0; jj < 8; ++jj) s += spart[jj][tid];
        out[tid] = s;               // read output
    }
}

// Kernel 2: epilogue — E = sigmoid(dot+be); nm = mem*(1-st*E) + st*a.
// 64 blocks x 256 thr x f32x4. ~1 MB traffic, ~3 us.
__global__ void __launch_bounds__(256)
epilogue_kernel(const float* __restrict__ ws, const float* __restrict__ be,
                const float* __restrict__ mem, const float* __restrict__ state,
                float* __restrict__ nm) {
    const int i = blockIdx.x * 256 + threadIdx.x;    // f32x4 index, 0..16383
    const int r = i * 4;
    const f32x4 d  = reinterpret_cast<const f32x4*>(ws + 512)[i];
    const f32x4 bv = reinterpret_cast<const f32x4*>(be)[i];
    const f32x4 mv = reinterpret_cast<const f32x4*>(mem)[i];
    const float st = state[r >> 7];
    const f32x4 av = *reinterpret_cast<const f32x4*>(ws + 128 + (r & 127));
    f32x4 o;
    o.x = mv.x * (1.f - st * (1.f / (1.f + expf(-(d.x + bv.x))))) + st * av.x;
    o.y = mv.y * (1.f - st * (1.f / (1.f + expf(-(d.y + bv.y))))) + st * av.y;
    o.z = mv.z * (1.f - st * (1.f / (1.f + expf(-(d.z + bv.z))))) + st * av.z;
    o.w = mv.w * (1.f - st * (1.f / (1.f + expf(-(d.w + bv.w))))) + st * av.w;
    __builtin_nontemporal_store(o, reinterpret_cast<f32x4*>(nm) + i);
}

// ---------------------------------------------------------------------------
extern "C" void kernel_launch(void* const* d_in, const int* in_sizes, int n_in,
                              void* d_out, int out_size, void* d_ws, size_t ws_size,
                              hipStream_t stream) {
    const float* x     = (const float*)d_in[0];
    const float* prev  = (const float*)d_in[1];
    const float* mem   = (const float*)d_in[2];
    const float* Wk    = (const float*)d_in[3];
    const float* bk    = (const float*)d_in[4];
    const float* Wbeta = (const float*)d_in[5];
    const float* bbeta = (const float*)d_in[6];
    const float* Wg    = (const float*)d_in[7];
    const float* bg    = (const float*)d_in[8];
    // d_in[9]=Ws, d_in[10]=bs, d_in[11]=Wgamma, d_in[12]=bgamma : dead outputs, skipped
    const float* We    = (const float*)d_in[13];
    const float* be    = (const float*)d_in[14];
    const float* Wa    = (const float*)d_in[15];
    const float* ba    = (const float*)d_in[16];

    float* out = (float*)d_out;   // [0..127]=read [128..639]=state [640..)=new_memory
    float* ws  = (float*)d_ws;    // [0..255]=k,a  [512..)=dots

    fused1_kernel<<<DOT_BLOCKS + 1, 1024, 0, stream>>>(
        x, We, Wk, bk, Wa, ba, Wbeta, bbeta, Wg, bg, mem, prev, ws, out);
    epilogue_kernel<<<NM / (256 * 4), 256, 0, stream>>>(
        ws, be, mem, out + M, out + M + N);
}